// Round 1
// baseline (240.687 us; speedup 1.0000x reference)
//
#include <hip/hip_runtime.h>
#include <hip/hip_bf16.h>
#include <math.h>

// FeedForwardQuantum — Round 7: fully-fused single kernel, ZERO d_ws usage.
// Theory: the two 256 MiB fillBufferAligned dispatches (85 µs) in the timed
// stream are the harness re-poisoning d_ws. This version recomputes q per
// block, computes h-tiles on the VALU directly into swizzled LDS (bf16),
// and converts w2 fp32->bf16 in-flight during staging. No prep, no gemm1,
// no h round-trip, no workspace.
// Structure: 128x256 tile, 8 waves (64x64 each), BK=64, double-buffered LDS
// (103 KiB), 1 barrier per K-step, B prefetched one MFMA-phase ahead.
// Frag layout / XOR-16B-block swizzle / MFMA orientation copied verbatim from
// the verified gemm2 (bank-conflict-free, absmax 0.0039).

typedef __attribute__((ext_vector_type(8))) short short8;
typedef __attribute__((ext_vector_type(4))) float fx4;

constexpr int EDIM = 512;
constexpr int FDIM = 2048;
constexpr int NQ   = 10;
constexpr int BM   = 128;
constexpr int BN   = 256;
constexpr int BK   = 64;
constexpr int NCH  = FDIM / BK;   // 32

__device__ __forceinline__ unsigned bits2(__hip_bfloat162 h) {
    union { __hip_bfloat162 h; unsigned u; } v; v.h = h; return v.u;
}

// h for 8 consecutive f (= k) values x 2 rows; fp32 math identical to gemm1.
__device__ __forceinline__ void hcomp(
    int k1, int fg, const float* __restrict__ w1, const float* __restrict__ b1,
    const float* q0, const float* q1, float* hv0, float* hv1)
{
    const float* w1p = w1 + (size_t)(k1 + fg * 8) * NQ;   // 320B contiguous, 16B-aligned
    float b1v[8];
    *(float4*)(b1v)     = *(const float4*)(b1 + k1 + fg * 8);
    *(float4*)(b1v + 4) = *(const float4*)(b1 + k1 + fg * 8 + 4);
    #pragma unroll
    for (int g = 0; g < 2; ++g) {          // two groups of 4 rows (40 floats each)
        float wv[40];
        #pragma unroll
        for (int u = 0; u < 10; ++u)
            ((float4*)wv)[u] = ((const float4*)(w1p + g * 40))[u];
        #pragma unroll
        for (int j = 0; j < 4; ++j) {
            float s0 = b1v[g * 4 + j], s1 = s0;
            #pragma unroll
            for (int w = 0; w < NQ; ++w) {
                s0 = fmaf(q0[w], wv[j * 10 + w], s0);
                s1 = fmaf(q1[w], wv[j * 10 + w], s1);
            }
            hv0[g * 4 + j] = s0; hv1[g * 4 + j] = s1;
        }
    }
}

__global__ __launch_bounds__(512, 2) void fused(
    const float* __restrict__ x, const float* __restrict__ rx,
    const float* __restrict__ w1, const float* __restrict__ b1,
    const float* __restrict__ w2, const float* __restrict__ b2,
    float* __restrict__ out)
{
    __shared__ __align__(16) ushort As[2][BM * BK];   // 32 KiB  (h tiles, bf16)
    __shared__ __align__(16) ushort Bs[2][BN * BK];   // 64 KiB  (w2 tiles, bf16)
    __shared__ float qs[BM][NQ];                      // 5 KiB

    const int tid = threadIdx.x;
    const int m0  = blockIdx.x * BM;
    const int n0  = blockIdx.y * BN;

    // ---- q prologue: closed-form quantum layer (verbatim math from gemm1) ----
    if (tid < BM) {
        const float* xr = x + (size_t)(m0 + tid) * EDIM;
        float4 xa = *(const float4*)xr;
        float4 xb = *(const float4*)(xr + 4);
        float2 xc = *(const float2*)(xr + 8);
        float xv[NQ] = {xa.x, xa.y, xa.z, xa.w, xb.x, xb.y, xb.z, xb.w, xc.x, xc.y};
        float c[NQ];
        #pragma unroll
        for (int w = 0; w < NQ; ++w) c[w] = cosf(xv[w] + rx[w]);
        float p0 = c[1];
        #pragma unroll
        for (int w = 2; w < NQ; ++w) p0 *= c[w];
        qs[tid][0] = p0;
        float p = c[0];
        #pragma unroll
        for (int w = 1; w < NQ; ++w) { p *= c[w]; qs[tid][w] = p; }
    }
    __syncthreads();

    // ---- roles ----
    // h-compute: thread owns rows {2mg, 2mg+1} x 8 consecutive f (block fg)
    const int fg = tid & 7;
    const int mg = tid >> 3;
    float q0[NQ], q1[NQ];
    #pragma unroll
    for (int w = 0; w < NQ; ++w) { q0[w] = qs[2 * mg][w]; q1[w] = qs[2 * mg + 1][w]; }

    // B staging: thread owns row brow, 32-float half kh of the BK slice
    const int brow = tid >> 1;
    const int kh   = tid & 1;
    const float* w2base = w2 + (size_t)(n0 + brow) * FDIM + kh * 32;

    // MFMA fragment roles (identical to verified gemm2)
    const int wave = tid >> 6, lane = tid & 63;
    const int quad = lane >> 4, l16 = lane & 15;
    const int wm = wave >> 2, wn = wave & 3;        // 2 x 4 waves, 64x64 each
    const int swz = l16 & 7;
    int aro[4], bro[4];
    #pragma unroll
    for (int t = 0; t < 4; ++t) {
        aro[t] = (wm * 64 + t * 16 + l16) * BK;
        bro[t] = (wn * 64 + t * 16 + l16) * BK;
    }

    fx4 acc[4][4];
    #pragma unroll
    for (int a = 0; a < 4; ++a)
        #pragma unroll
        for (int b = 0; b < 4; ++b) acc[a][b] = fx4{0.f, 0.f, 0.f, 0.f};

    // ---- stage chunk 0 into buf 0 ----
    float bqv[32];
    float hv0[8], hv1[8];
    #pragma unroll
    for (int u = 0; u < 8; ++u) ((float4*)bqv)[u] = ((const float4*)w2base)[u];
    hcomp(0, fg, w1, b1, q0, q1, hv0, hv1);
    {
        #pragma unroll
        for (int g = 0; g < 4; ++g) {
            short8 o;
            #pragma unroll
            for (int p = 0; p < 4; ++p) {
                unsigned u = bits2(__float22bfloat162_rn(
                    make_float2(bqv[g * 8 + 2 * p], bqv[g * 8 + 2 * p + 1])));
                o[2 * p] = (short)(u & 0xFFFFu); o[2 * p + 1] = (short)(u >> 16);
            }
            const int blk = (kh * 4 + g) ^ (brow & 7);
            *(short8*)&Bs[0][brow * BK + blk * 8] = o;
        }
        #pragma unroll
        for (int r2 = 0; r2 < 2; ++r2) {
            const int row = 2 * mg + r2;
            const float* hv = r2 ? hv1 : hv0;     // r2 is unroll-static
            short8 o;
            #pragma unroll
            for (int p = 0; p < 4; ++p) {
                unsigned u = bits2(__float22bfloat162_rn(
                    make_float2(fmaxf(hv[2 * p], 0.f), fmaxf(hv[2 * p + 1], 0.f))));
                o[2 * p] = (short)(u & 0xFFFFu); o[2 * p + 1] = (short)(u >> 16);
            }
            const int blk = fg ^ (row & 7);
            *(short8*)&As[0][row * BK + blk * 8] = o;
        }
    }
    __syncthreads();

    // ---- main loop: compute chunk i from buf cur; stage chunk i+1 -> nxt ----
    for (int i = 0; i < NCH - 1; ++i) {
        const int cur = i & 1, nxt = cur ^ 1;

        // prefetch B chunk i+1 (consumed after MFMA — latency hidden)
        #pragma unroll
        for (int u = 0; u < 8; ++u)
            ((float4*)bqv)[u] = ((const float4*)(w2base + (size_t)(i + 1) * BK))[u];

        // frags + MFMA on chunk i
        #pragma unroll
        for (int hf = 0; hf < 2; ++hf) {
            const int blk = ((hf * 4 + quad) ^ swz) * 8;
            short8 af[4], bfq[4];
            #pragma unroll
            for (int t = 0; t < 4; ++t) {
                af[t]  = *(const short8*)&As[cur][aro[t] + blk];
                bfq[t] = *(const short8*)&Bs[cur][bro[t] + blk];
            }
            #pragma unroll
            for (int mt = 0; mt < 4; ++mt)
                #pragma unroll
                for (int nt = 0; nt < 4; ++nt)
                    acc[mt][nt] = __builtin_amdgcn_mfma_f32_16x16x32_bf16(
                        af[mt], bfq[nt], acc[mt][nt], 0, 0, 0);
        }

        // h for chunk i+1 (VALU, overlaps MFMA pipe)
        hcomp((i + 1) * BK, fg, w1, b1, q0, q1, hv0, hv1);

        // write chunk i+1 into nxt (nxt's readers finished before last barrier)
        #pragma unroll
        for (int g = 0; g < 4; ++g) {
            short8 o;
            #pragma unroll
            for (int p = 0; p < 4; ++p) {
                unsigned u = bits2(__float22bfloat162_rn(
                    make_float2(bqv[g * 8 + 2 * p], bqv[g * 8 + 2 * p + 1])));
                o[2 * p] = (short)(u & 0xFFFFu); o[2 * p + 1] = (short)(u >> 16);
            }
            const int blk = (kh * 4 + g) ^ (brow & 7);
            *(short8*)&Bs[nxt][brow * BK + blk * 8] = o;
        }
        #pragma unroll
        for (int r2 = 0; r2 < 2; ++r2) {
            const int row = 2 * mg + r2;
            const float* hv = r2 ? hv1 : hv0;
            short8 o;
            #pragma unroll
            for (int p = 0; p < 4; ++p) {
                unsigned u = bits2(__float22bfloat162_rn(
                    make_float2(fmaxf(hv[2 * p], 0.f), fmaxf(hv[2 * p + 1], 0.f))));
                o[2 * p] = (short)(u & 0xFFFFu); o[2 * p + 1] = (short)(u >> 16);
            }
            const int blk = fg ^ (row & 7);
            *(short8*)&As[nxt][row * BK + blk * 8] = o;
        }
        __syncthreads();
    }

    // ---- last chunk (buf 1, no staging) ----
    {
        const int cur = (NCH - 1) & 1;
        #pragma unroll
        for (int hf = 0; hf < 2; ++hf) {
            const int blk = ((hf * 4 + quad) ^ swz) * 8;
            short8 af[4], bfq[4];
            #pragma unroll
            for (int t = 0; t < 4; ++t) {
                af[t]  = *(const short8*)&As[cur][aro[t] + blk];
                bfq[t] = *(const short8*)&Bs[cur][bro[t] + blk];
            }
            #pragma unroll
            for (int mt = 0; mt < 4; ++mt)
                #pragma unroll
                for (int nt = 0; nt < 4; ++nt)
                    acc[mt][nt] = __builtin_amdgcn_mfma_f32_16x16x32_bf16(
                        af[mt], bfq[nt], acc[mt][nt], 0, 0, 0);
        }
    }

    // ---- epilogue: + b2 (C layout: col=l16, row=quad*4+r — verified) ----
    float bb[4];
    #pragma unroll
    for (int nt = 0; nt < 4; ++nt) bb[nt] = b2[n0 + wn * 64 + nt * 16 + l16];
    #pragma unroll
    for (int mt = 0; mt < 4; ++mt) {
        const int mbase = m0 + wm * 64 + mt * 16 + quad * 4;
        #pragma unroll
        for (int nt = 0; nt < 4; ++nt) {
            const int n = n0 + wn * 64 + nt * 16 + l16;
            #pragma unroll
            for (int r = 0; r < 4; ++r)
                out[(size_t)(mbase + r) * EDIM + n] = acc[mt][nt][r] + bb[nt];
        }
    }
}

extern "C" void kernel_launch(void* const* d_in, const int* in_sizes, int n_in,
                              void* d_out, int out_size, void* d_ws, size_t ws_size,
                              hipStream_t stream) {
    const float* x  = (const float*)d_in[0];
    const float* rx = (const float*)d_in[1];
    const float* w1 = (const float*)d_in[2];
    const float* b1 = (const float*)d_in[3];
    const float* w2 = (const float*)d_in[4];
    const float* b2 = (const float*)d_in[5];

    const int M = in_sizes[0] / EDIM;   // 16384

    // ZERO workspace usage — the whole point of this round.
    (void)d_ws; (void)ws_size; (void)n_in; (void)out_size;

    hipLaunchKernelGGL(fused, dim3(M / BM, EDIM / BN), dim3(512), 0, stream,
                       x, rx, w1, b1, w2, b2, (float*)d_out);
}

// Round 2
// 178.311 us; speedup vs baseline: 1.3498x; 1.3498x over previous
//
#include <hip/hip_runtime.h>
#include <hip/hip_bf16.h>
#include <math.h>

// FeedForwardQuantum — Round 8: fused v2.
// Fixes vs v1 (172 us, 75% stalled): (1) 128x128 tile / 256 thr / 70 KiB LDS
// -> 2 blocks/CU restores inter-block MFMA<->staging overlap; (2) w1 via
// wave-uniform SCALAR loads (readfirstlane-forced) -> s_load + v_fmac(sgpr),
// kills the 160 KiB/iter L1 storm and the 40-reg wv array; (3) one m-row per
// lane (qv = 10 VGPRs, was 40); lean register footprint, no spills.
// MFMA core / swizzle / epilogue layout verbatim from the verified gemm2
// (round-0, absmax 0.0039) and v1 (also passed).
// Zero d_ws usage (resolves the poison-fill question).

typedef __attribute__((ext_vector_type(8))) short short8;
typedef __attribute__((ext_vector_type(4))) float fx4;

constexpr int EDIM = 512;
constexpr int FDIM = 2048;
constexpr int NQ   = 10;
constexpr int BM   = 128;
constexpr int BN   = 128;
constexpr int BK   = 64;
constexpr int NCH  = FDIM / BK;   // 32

__device__ __forceinline__ unsigned bits2(__hip_bfloat162 h) {
    union { __hip_bfloat162 h; unsigned u; } v; v.h = h; return v.u;
}

// h for 32 consecutive f at one m-row. w1/b1 addresses are wave-uniform
// (fb from readfirstlane) -> scalar loads; qv per-lane; accum fp32.
__device__ __forceinline__ void hcomp32(
    int k1, int fb, const float* __restrict__ w1, const float* __restrict__ b1,
    const float* qv, float* hv)
{
    const float* w1p = w1 + (size_t)(k1 + fb) * NQ;
    const float* b1p = b1 + k1 + fb;
    #pragma unroll
    for (int ff = 0; ff < 32; ++ff) {
        float s = b1p[ff];                       // uniform -> s_load
        #pragma unroll
        for (int w = 0; w < NQ; ++w)
            s = fmaf(w1p[ff * NQ + w], qv[w], s); // sgpr * vgpr + vgpr
        hv[ff] = s;
    }
}

__global__ __launch_bounds__(256, 2) void fused(
    const float* __restrict__ x, const float* __restrict__ rx,
    const float* __restrict__ w1, const float* __restrict__ b1,
    const float* __restrict__ w2, const float* __restrict__ b2,
    float* __restrict__ out)
{
    __shared__ __align__(16) ushort As[2][BM * BK];   // 32 KiB (h, bf16)
    __shared__ __align__(16) ushort Bs[2][BN * BK];   // 32 KiB (w2, bf16)
    __shared__ float qs[BM][NQ];                      // 5 KiB

    const int tid = threadIdx.x;
    const int m0  = blockIdx.x * BM;
    const int n0  = blockIdx.y * BN;

    // ---- q prologue (verbatim math from verified gemm1) ----
    if (tid < BM) {
        const float* xr = x + (size_t)(m0 + tid) * EDIM;
        float4 xa = *(const float4*)xr;
        float4 xb = *(const float4*)(xr + 4);
        float2 xc = *(const float2*)(xr + 8);
        float xv[NQ] = {xa.x, xa.y, xa.z, xa.w, xb.x, xb.y, xb.z, xb.w, xc.x, xc.y};
        float c[NQ];
        #pragma unroll
        for (int w = 0; w < NQ; ++w) c[w] = cosf(xv[w] + rx[w]);
        float p0 = c[1];
        #pragma unroll
        for (int w = 2; w < NQ; ++w) p0 *= c[w];
        qs[tid][0] = p0;
        float p = c[0];
        #pragma unroll
        for (int w = 1; w < NQ; ++w) { p *= c[w]; qs[tid][w] = p; }
    }
    __syncthreads();

    const int wave = tid >> 6, lane = tid & 63;

    // ---- h-compute role: one m-row per lane, wave-uniform 32-f slice ----
    const int hrow = (wave >> 1) * 64 + lane;                       // 0..127
    const int fb   = __builtin_amdgcn_readfirstlane((wave & 1) * 32); // 0 or 32
    float qv[NQ];
    #pragma unroll
    for (int w = 0; w < NQ; ++w) qv[w] = qs[hrow][w];

    // ---- B-staging role: row brow, 32-float half kh ----
    const int brow = tid >> 1;
    const int kh   = tid & 1;
    const float* w2base = w2 + (size_t)(n0 + brow) * FDIM + kh * 32;

    // ---- MFMA fragment roles (verbatim from verified round-0 gemm2) ----
    const int quad = lane >> 4, l16 = lane & 15;
    const int wm = wave >> 1, wn = wave & 1;
    const int swz = l16 & 7;
    int aro[4], bro[4];
    #pragma unroll
    for (int t = 0; t < 4; ++t) {
        aro[t] = (wm * 64 + t * 16 + l16) * BK;
        bro[t] = (wn * 64 + t * 16 + l16) * BK;
    }

    fx4 acc[4][4];
    #pragma unroll
    for (int a = 0; a < 4; ++a)
        #pragma unroll
        for (int b = 0; b < 4; ++b) acc[a][b] = fx4{0.f, 0.f, 0.f, 0.f};

    float bqv[32], hv[32];

    // ---- stage chunk 0 -> buf 0 ----
    #pragma unroll
    for (int u = 0; u < 8; ++u) ((float4*)bqv)[u] = ((const float4*)w2base)[u];
    hcomp32(0, fb, w1, b1, qv, hv);
    #pragma unroll
    for (int g = 0; g < 4; ++g) {                       // B pack+write
        short8 o;
        #pragma unroll
        for (int p = 0; p < 4; ++p) {
            unsigned u = bits2(__float22bfloat162_rn(
                make_float2(bqv[g * 8 + 2 * p], bqv[g * 8 + 2 * p + 1])));
            o[2 * p] = (short)(u & 0xFFFFu); o[2 * p + 1] = (short)(u >> 16);
        }
        const int blk = (kh * 4 + g) ^ (brow & 7);
        *(short8*)&Bs[0][brow * BK + blk * 8] = o;
    }
    #pragma unroll
    for (int g = 0; g < 4; ++g) {                       // A(h) relu+pack+write
        short8 o;
        #pragma unroll
        for (int p = 0; p < 4; ++p) {
            unsigned u = bits2(__float22bfloat162_rn(
                make_float2(fmaxf(hv[g * 8 + 2 * p], 0.f),
                            fmaxf(hv[g * 8 + 2 * p + 1], 0.f))));
            o[2 * p] = (short)(u & 0xFFFFu); o[2 * p + 1] = (short)(u >> 16);
        }
        const int blk = ((fb >> 3) + g) ^ (hrow & 7);
        *(short8*)&As[0][hrow * BK + blk * 8] = o;
    }
    __syncthreads();

    // ---- main loop ----
    for (int i = 0; i < NCH - 1; ++i) {
        const int cur = i & 1, nxt = cur ^ 1;

        // B prefetch for chunk i+1 (latency hides under MFMA)
        #pragma unroll
        for (int u = 0; u < 8; ++u)
            ((float4*)bqv)[u] = ((const float4*)(w2base + (size_t)(i + 1) * BK))[u];

        // frags + MFMA on chunk i
        #pragma unroll
        for (int hf = 0; hf < 2; ++hf) {
            const int blk = ((hf * 4 + quad) ^ swz) * 8;
            short8 af[4], bfq[4];
            #pragma unroll
            for (int t = 0; t < 4; ++t) {
                af[t]  = *(const short8*)&As[cur][aro[t] + blk];
                bfq[t] = *(const short8*)&Bs[cur][bro[t] + blk];
            }
            #pragma unroll
            for (int mt = 0; mt < 4; ++mt)
                #pragma unroll
                for (int nt = 0; nt < 4; ++nt)
                    acc[mt][nt] = __builtin_amdgcn_mfma_f32_16x16x32_bf16(
                        af[mt], bfq[nt], acc[mt][nt], 0, 0, 0);
        }

        // h for chunk i+1 (scalar w1, VALU fma — overlaps MFMA pipe)
        hcomp32((i + 1) * BK, fb, w1, b1, qv, hv);

        // pack + write chunk i+1 -> nxt
        #pragma unroll
        for (int g = 0; g < 4; ++g) {
            short8 o;
            #pragma unroll
            for (int p = 0; p < 4; ++p) {
                unsigned u = bits2(__float22bfloat162_rn(
                    make_float2(bqv[g * 8 + 2 * p], bqv[g * 8 + 2 * p + 1])));
                o[2 * p] = (short)(u & 0xFFFFu); o[2 * p + 1] = (short)(u >> 16);
            }
            const int blk = (kh * 4 + g) ^ (brow & 7);
            *(short8*)&Bs[nxt][brow * BK + blk * 8] = o;
        }
        #pragma unroll
        for (int g = 0; g < 4; ++g) {
            short8 o;
            #pragma unroll
            for (int p = 0; p < 4; ++p) {
                unsigned u = bits2(__float22bfloat162_rn(
                    make_float2(fmaxf(hv[g * 8 + 2 * p], 0.f),
                                fmaxf(hv[g * 8 + 2 * p + 1], 0.f))));
                o[2 * p] = (short)(u & 0xFFFFu); o[2 * p + 1] = (short)(u >> 16);
            }
            const int blk = ((fb >> 3) + g) ^ (hrow & 7);
            *(short8*)&As[nxt][hrow * BK + blk * 8] = o;
        }
        __syncthreads();
    }

    // ---- last chunk (no staging) ----
    {
        const int cur = (NCH - 1) & 1;
        #pragma unroll
        for (int hf = 0; hf < 2; ++hf) {
            const int blk = ((hf * 4 + quad) ^ swz) * 8;
            short8 af[4], bfq[4];
            #pragma unroll
            for (int t = 0; t < 4; ++t) {
                af[t]  = *(const short8*)&As[cur][aro[t] + blk];
                bfq[t] = *(const short8*)&Bs[cur][bro[t] + blk];
            }
            #pragma unroll
            for (int mt = 0; mt < 4; ++mt)
                #pragma unroll
                for (int nt = 0; nt < 4; ++nt)
                    acc[mt][nt] = __builtin_amdgcn_mfma_f32_16x16x32_bf16(
                        af[mt], bfq[nt], acc[mt][nt], 0, 0, 0);
        }
    }

    // ---- epilogue: + b2 (verified C layout: col=l16, row=quad*4+r) ----
    float bb[4];
    #pragma unroll
    for (int nt = 0; nt < 4; ++nt) bb[nt] = b2[n0 + wn * 64 + nt * 16 + l16];
    #pragma unroll
    for (int mt = 0; mt < 4; ++mt) {
        const int mbase = m0 + wm * 64 + mt * 16 + quad * 4;
        #pragma unroll
        for (int nt = 0; nt < 4; ++nt) {
            const int n = n0 + wn * 64 + nt * 16 + l16;
            #pragma unroll
            for (int r = 0; r < 4; ++r)
                out[(size_t)(mbase + r) * EDIM + n] = acc[mt][nt][r] + bb[nt];
        }
    }
}

extern "C" void kernel_launch(void* const* d_in, const int* in_sizes, int n_in,
                              void* d_out, int out_size, void* d_ws, size_t ws_size,
                              hipStream_t stream) {
    const float* x  = (const float*)d_in[0];
    const float* rx = (const float*)d_in[1];
    const float* w1 = (const float*)d_in[2];
    const float* b1 = (const float*)d_in[3];
    const float* w2 = (const float*)d_in[4];
    const float* b2 = (const float*)d_in[5];

    const int M = in_sizes[0] / EDIM;   // 16384

    (void)d_ws; (void)ws_size; (void)n_in; (void)out_size;  // zero ws usage

    hipLaunchKernelGGL(fused, dim3(M / BM, EDIM / BN), dim3(256), 0, stream,
                       x, rx, w1, b1, w2, b2, (float*)d_out);
}

// Round 4
// 146.875 us; speedup vs baseline: 1.6387x; 1.2140x over previous
//
#include <hip/hip_runtime.h>
#include <hip/hip_bf16.h>
#include <math.h>

// FeedForwardQuantum — Round 10: Round-9 kernel + missing ushort8 typedef.
// Decoupled (ws-poison fills proven unconditional, so d_ws is free).
// prep + gemm1 verbatim from the verified round-0 build.
// gemm2 = T2+T3+T4+T5 counted-vmcnt phase schedule:
//   256x128 tile, 512 thr / 8 waves (each wave = the verified 64x64 core),
//   BK=64, dbuf LDS 96 KiB, 4 phases per K-tile, vmcnt(6) in main loop
//   (never drained to 0), setprio(1) around each 8-MFMA quadrant.

typedef __attribute__((ext_vector_type(8))) short short8;
typedef __attribute__((ext_vector_type(8))) unsigned short ushort8;
typedef __attribute__((ext_vector_type(4))) float fx4;

constexpr int EDIM = 512;
constexpr int FDIM = 2048;
constexpr int NQ   = 10;
constexpr int BK   = 64;
constexpr int BM2  = 256;          // gemm2 tile
constexpr int BN2  = 128;
constexpr int NT2  = FDIM / BK;    // 32 K-tiles
constexpr int ABUF = BM2 * BK;     // 16384 ushorts
constexpr int BBUF = BN2 * BK;     // 8192 ushorts

__device__ __forceinline__ ushort f2bf(float f) {
    union { float f; unsigned u; } v; v.f = f;
    unsigned u = v.u + 0x7FFFu + ((v.u >> 16) & 1u);
    return (ushort)(u >> 16);
}
__device__ __forceinline__ unsigned bits2(__hip_bfloat162 h) {
    union { __hip_bfloat162 h; unsigned u; } v; v.h = h; return v.u;
}
__device__ __forceinline__ void gload_lds16(const void* g, void* l) {
    __builtin_amdgcn_global_load_lds(
        (const __attribute__((address_space(1))) void*)g,
        (__attribute__((address_space(3))) void*)l, 16, 0, 0);
}

#define SBAR()   __builtin_amdgcn_s_barrier()
#define LGKM0()  asm volatile("s_waitcnt lgkmcnt(0)" ::: "memory")
#define SCHED0() __builtin_amdgcn_sched_barrier(0)
#define VMCNT6() asm volatile("s_waitcnt vmcnt(6)" ::: "memory")
#define VMCNT0() asm volatile("s_waitcnt vmcnt(0)" ::: "memory")

// ---- prep: w2 f32 -> bf16 (verbatim round-0) ----
__global__ void prep(const float* __restrict__ w2, ushort* __restrict__ w2b) {
    int gid = blockIdx.x * blockDim.x + threadIdx.x;
    int np  = gridDim.x * blockDim.x;
    for (int i = gid; i < EDIM * FDIM / 4; i += np) {
        float4 v = ((const float4*)w2)[i];
        ushort4 o; o.x = f2bf(v.x); o.y = f2bf(v.y); o.z = f2bf(v.z); o.w = f2bf(v.w);
        ((ushort4*)w2b)[i] = o;
    }
}

// ---- gemm1 (verbatim round-0): h = relu(q @ w1^T + b1), bf16 out ----
__global__ __launch_bounds__(256, 2) void gemm1(
    const float* __restrict__ x, const float* __restrict__ rx,
    const float* __restrict__ w1, const float* __restrict__ b1,
    ushort* __restrict__ h, int m_base)
{
    __shared__ float qs[32][NQ];
    const int tid = threadIdx.x;
    const int m0  = m_base + blockIdx.x * 32;

    if (tid < 32) {
        const float* xr = x + (size_t)(m0 + tid) * EDIM;
        float c[NQ], q[NQ];
        #pragma unroll
        for (int w = 0; w < NQ; ++w) c[w] = cosf(xr[w] + rx[w]);
        float p0 = c[1];
        #pragma unroll
        for (int w = 2; w < NQ; ++w) p0 *= c[w];
        q[0] = p0;
        float p = c[0];
        #pragma unroll
        for (int w = 1; w < NQ; ++w) { p *= c[w]; q[w] = p; }
        #pragma unroll
        for (int w = 0; w < NQ; ++w) qs[tid][w] = q[w];
    }
    __syncthreads();

    float wv[80];
    {
        const float4* wp = (const float4*)(w1 + (size_t)tid * 80);
        #pragma unroll
        for (int u = 0; u < 20; ++u) ((float4*)wv)[u] = wp[u];
    }
    float bv[8];
    {
        float4 a = *(const float4*)(b1 + tid * 8);
        float4 b = *(const float4*)(b1 + tid * 8 + 4);
        bv[0]=a.x; bv[1]=a.y; bv[2]=a.z; bv[3]=a.w;
        bv[4]=b.x; bv[5]=b.y; bv[6]=b.z; bv[7]=b.w;
    }
    ushort* hrow = h + (size_t)m0 * FDIM + tid * 8;

    for (int m = 0; m < 32; ++m) {
        float qv[NQ];
        #pragma unroll
        for (int w = 0; w < NQ; ++w) qv[w] = qs[m][w];
        float a[8];
        #pragma unroll
        for (int r = 0; r < 8; ++r) a[r] = bv[r];
        #pragma unroll
        for (int w = 0; w < NQ; ++w)
            #pragma unroll
            for (int r = 0; r < 8; ++r)
                a[r] = fmaf(qv[w], wv[r * 10 + w], a[r]);
        ushort8 o;
        #pragma unroll
        for (int r = 0; r < 4; ++r) {
            unsigned p = bits2(__float22bfloat162_rn(
                make_float2(fmaxf(a[2*r], 0.f), fmaxf(a[2*r+1], 0.f))));
            o[2*r]   = (ushort)(p & 0xFFFFu);
            o[2*r+1] = (ushort)(p >> 16);
        }
        *(ushort8*)(hrow + (size_t)m * FDIM) = o;
    }
}

// ---- gemm2: out = h @ w2b^T + b2 — 8-wave counted-vmcnt phase schedule ----
__global__ __launch_bounds__(512, 2) void gemm2(
    const ushort* __restrict__ h,     // [M][FDIM] bf16
    const ushort* __restrict__ w2b,   // [EDIM][FDIM] bf16
    const float* __restrict__ b2,
    float* __restrict__ out, int m_base)
{
    __shared__ __align__(16) ushort As[2 * ABUF];   // 64 KiB
    __shared__ __align__(16) ushort Bs[2 * BBUF];   // 32 KiB

    const int tid  = threadIdx.x;
    const int m0   = m_base + blockIdx.x * BM2;
    const int n0   = blockIdx.y * BN2;
    const int wave = tid >> 6, lane = tid & 63;
    const int quad = lane >> 4, l16 = lane & 15;
    const int wm   = wave >> 1, wn = wave & 1;      // 4x2 waves, 64x64 each
    const int swz  = l16 & 7;

    // staging roles: sweep u covers rows u*64 + (tid>>3); 16B-block bl
    const int srow = tid >> 3;
    const int bl   = (tid & 7) ^ (srow & 7);
    const ushort* pA[4]; const ushort* pB[2];
    #pragma unroll
    for (int u = 0; u < 4; ++u)
        pA[u] = h + (size_t)(m0 + u * 64 + srow) * FDIM + bl * 8;
    #pragma unroll
    for (int u = 0; u < 2; ++u)
        pB[u] = w2b + (size_t)(n0 + u * 64 + srow) * FDIM + bl * 8;

    // fragment-read row offsets (verified round-0 core, wm scaled to 4)
    int aro[4], bro[4];
    #pragma unroll
    for (int t = 0; t < 4; ++t) {
        aro[t] = (wm * 64 + t * 16 + l16) * BK;
        bro[t] = (wn * 64 + t * 16 + l16) * BK;
    }

    fx4 acc[4][4];
    #pragma unroll
    for (int a = 0; a < 4; ++a)
        #pragma unroll
        for (int b = 0; b < 4; ++b) acc[a][b] = fx4{0.f, 0.f, 0.f, 0.f};

#define RDA(Ab, PAIR, fr) do { \
    _Pragma("unroll") for (int m_ = 0; m_ < 2; ++m_) \
    _Pragma("unroll") for (int hf = 0; hf < 2; ++hf) \
        fr[m_][hf] = *(const short8*)&(Ab)[aro[(PAIR)*2+m_] + (((hf*4+quad)^swz)<<3)]; \
} while(0)
#define RDB(Bb, PAIR, fr) do { \
    _Pragma("unroll") for (int n_ = 0; n_ < 2; ++n_) \
    _Pragma("unroll") for (int hf = 0; hf < 2; ++hf) \
        fr[n_][hf] = *(const short8*)&(Bb)[bro[(PAIR)*2+n_] + (((hf*4+quad)^swz)<<3)]; \
} while(0)
#define MMQ(Af, Bf, MO, NO) do { \
    _Pragma("unroll") for (int hf = 0; hf < 2; ++hf) \
    _Pragma("unroll") for (int m_ = 0; m_ < 2; ++m_) \
    _Pragma("unroll") for (int n_ = 0; n_ < 2; ++n_) \
        acc[(MO)+m_][(NO)+n_] = __builtin_amdgcn_mfma_f32_16x16x32_bf16( \
            Af[m_][hf], Bf[n_][hf], acc[(MO)+m_][(NO)+n_], 0, 0, 0); \
} while(0)

    // ---- prologue: stage tiles 0 and 1 ----
    #pragma unroll
    for (int u = 0; u < 4; ++u) { gload_lds16(pA[u], As + u * 4096 + wave * 512); pA[u] += BK; }
    #pragma unroll
    for (int u = 0; u < 2; ++u) { gload_lds16(pB[u], Bs + u * 4096 + wave * 512); pB[u] += BK; }
    #pragma unroll
    for (int u = 0; u < 4; ++u) { gload_lds16(pA[u], As + ABUF + u * 4096 + wave * 512); pA[u] += BK; }
    #pragma unroll
    for (int u = 0; u < 2; ++u) { gload_lds16(pB[u], Bs + BBUF + u * 4096 + wave * 512); pB[u] += BK; }
    VMCNT6();       // tile 0 landed (tile 1's 6 still in flight)
    SBAR();

    // ---- K-tile body: 4 phases, MODE 0=stage t+2, 1=last prefetch drain, 2=tail ----
#define KTILE(T, MODE) do { \
    const ushort* Ab = As + ((T) & 1) * ABUF; \
    const ushort* Bb = Bs + ((T) & 1) * BBUF; \
    ushort* Aw = As + ((T) & 1) * ABUF; \
    ushort* Bw = Bs + ((T) & 1) * BBUF; \
    short8 a0[2][2], a1[2][2], b0[2][2], b1[2][2]; \
    /* ph0: A-pair0 + B-pair0 reads; MFMA quad (0,0) */ \
    RDA(Ab, 0, a0); RDB(Bb, 0, b0); \
    SBAR(); LGKM0(); SCHED0(); \
    __builtin_amdgcn_s_setprio(1); MMQ(a0, b0, 0, 0); __builtin_amdgcn_s_setprio(0); \
    SBAR(); \
    /* ph1: B-pair1 reads; MFMA quad (0,2) */ \
    RDB(Bb, 1, b1); \
    SBAR(); LGKM0(); SCHED0(); \
    __builtin_amdgcn_s_setprio(1); MMQ(a0, b1, 0, 2); __builtin_amdgcn_s_setprio(0); \
    SBAR(); \
    /* ph2: A-pair1 reads + B-stage issue (B reads all drained); quad (2,2) */ \
    RDA(Ab, 1, a1); \
    if ((MODE) == 0) { \
        _Pragma("unroll") for (int u = 0; u < 2; ++u) { \
            gload_lds16(pB[u], Bw + u * 4096 + wave * 512); pB[u] += BK; } \
    } \
    SBAR(); LGKM0(); SCHED0(); \
    __builtin_amdgcn_s_setprio(1); MMQ(a1, b1, 2, 2); __builtin_amdgcn_s_setprio(0); \
    SBAR(); \
    /* ph3: A-stage issue (A reads drained); counted vmcnt; quad (2,0) */ \
    if ((MODE) == 0) { \
        _Pragma("unroll") for (int u = 0; u < 4; ++u) { \
            gload_lds16(pA[u], Aw + u * 4096 + wave * 512); pA[u] += BK; } \
        VMCNT6(); \
    } else if ((MODE) == 1) { VMCNT0(); } \
    SBAR(); \
    __builtin_amdgcn_s_setprio(1); MMQ(a1, b0, 2, 0); __builtin_amdgcn_s_setprio(0); \
    SBAR(); \
} while(0)

    for (int t = 0; t < NT2 - 2; ++t) KTILE(t, 0);
    KTILE(NT2 - 2, 1);
    KTILE(NT2 - 1, 2);

#undef KTILE
#undef MMQ
#undef RDA
#undef RDB

    // ---- epilogue: + b2 (verified C layout: col=l16 -> n, row=quad*4+r -> m) ----
    float bb[4];
    #pragma unroll
    for (int nt = 0; nt < 4; ++nt) bb[nt] = b2[n0 + wn * 64 + nt * 16 + l16];
    #pragma unroll
    for (int mt = 0; mt < 4; ++mt) {
        const int mbase = m0 + wm * 64 + mt * 16 + quad * 4;
        #pragma unroll
        for (int nt = 0; nt < 4; ++nt) {
            const int n = n0 + wn * 64 + nt * 16 + l16;
            #pragma unroll
            for (int r = 0; r < 4; ++r)
                out[(size_t)(mbase + r) * EDIM + n] = acc[mt][nt][r] + bb[nt];
        }
    }
}

extern "C" void kernel_launch(void* const* d_in, const int* in_sizes, int n_in,
                              void* d_out, int out_size, void* d_ws, size_t ws_size,
                              hipStream_t stream) {
    const float* x  = (const float*)d_in[0];
    const float* rx = (const float*)d_in[1];
    const float* w1 = (const float*)d_in[2];
    const float* b1 = (const float*)d_in[3];
    const float* w2 = (const float*)d_in[4];
    const float* b2 = (const float*)d_in[5];
    float* out = (float*)d_out;

    const int M = in_sizes[0] / EDIM;   // 16384

    const size_t w2bytes = (size_t)EDIM * FDIM * 2;
    ushort* w2b = (ushort*)d_ws;
    ushort* h   = (ushort*)((char*)d_ws + w2bytes);

    int Ms = M;   // slice if ws can't hold full h (full M needs 64 MiB)
    {
        size_t avail = (ws_size > w2bytes) ? ws_size - w2bytes : 0;
        int cap = (int)(avail / ((size_t)FDIM * 2));
        cap &= ~255;
        if (cap < 256) cap = 256;
        if (Ms > cap) Ms = cap;
    }

    hipLaunchKernelGGL(prep, dim3(256), dim3(256), 0, stream, w2, w2b);

    for (int mb = 0; mb < M; mb += Ms) {
        int cur = (M - mb < Ms) ? (M - mb) : Ms;
        hipLaunchKernelGGL(gemm1, dim3(cur / 32), dim3(256), 0, stream,
                           x, rx, w1, b1, h, mb);
        hipLaunchKernelGGL(gemm2, dim3(cur / BM2, EDIM / BN2), dim3(512), 0, stream,
                           h, w2b, b2, out, mb);
    }
}